// Round 1
// baseline (91.771 us; speedup 1.0000x reference)
//
#include <hip/hip_runtime.h>

// Problem: B=8192 all-pairs hinge ranking loss.
//   mask[i][j] = (time[i] < time[j]) && (event[i] == 1)
//   hinge[i][j] = relu(MARGIN - (risk[j] - risk[i]))
//   out = sum(hinge*mask) / sum(mask)   (0 if count==0)
// z (d_in[0]) is unused by the reference output.

#define BDIM 8192
#define MARGIN_F 1.0f

__global__ __launch_bounds__(256) void sgr_pair_kernel(
    const float* __restrict__ risk,
    const float* __restrict__ tim,
    const int*   __restrict__ event,
    double*      __restrict__ ws)   // ws[0]=total, ws[1]=count
{
    __shared__ float s_time[256];
    __shared__ float s_risk[256];

    const int t     = threadIdx.x;
    const int i     = blockIdx.x * 256 + t;
    const int jbase = blockIdx.y * 256;

    // Stage this block's j-tile into LDS (coalesced global loads).
    s_time[t] = tim[jbase + t];
    s_risk[t] = risk[jbase + t];
    __syncthreads();

    const float ti   = tim[i];
    const float rip1 = risk[i] + MARGIN_F;   // (MARGIN + risk[i]) - risk[j]
    const bool  ev   = (event[i] == 1);

    float sum = 0.0f;
    float cnt = 0.0f;
    if (ev) {
        #pragma unroll 8
        for (int j = 0; j < 256; ++j) {
            // Same address across the wave -> LDS broadcast, conflict-free.
            const float tj = s_time[j];
            const float rj = s_risk[j];
            const bool  m  = ti < tj;
            const float h  = fmaxf(rip1 - rj, 0.0f);
            sum += m ? h : 0.0f;
            cnt += m ? 1.0f : 0.0f;   // per-thread cnt <= 256, exact in fp32
        }
    }

    // Wave-64 shuffle reduction.
    #pragma unroll
    for (int off = 32; off > 0; off >>= 1) {
        sum += __shfl_down(sum, off, 64);
        cnt += __shfl_down(cnt, off, 64);
    }

    __shared__ float w_sum[4];
    __shared__ float w_cnt[4];
    const int wave = t >> 6;
    const int lane = t & 63;
    if (lane == 0) { w_sum[wave] = sum; w_cnt[wave] = cnt; }
    __syncthreads();

    if (t == 0) {
        const float bs = w_sum[0] + w_sum[1] + w_sum[2] + w_sum[3];
        const float bc = w_cnt[0] + w_cnt[1] + w_cnt[2] + w_cnt[3];
        // Global count ~16.7M sits at the fp32 2^24 edge; accumulate in double.
        atomicAdd(&ws[0], (double)bs);
        atomicAdd(&ws[1], (double)bc);
    }
}

__global__ void sgr_finalize_kernel(const double* __restrict__ ws,
                                    float* __restrict__ out)
{
    const double cnt = ws[1];
    out[0] = (cnt == 0.0) ? 0.0f : (float)(ws[0] / cnt);
}

extern "C" void kernel_launch(void* const* d_in, const int* in_sizes, int n_in,
                              void* d_out, int out_size, void* d_ws, size_t ws_size,
                              hipStream_t stream)
{
    // setup_inputs order: z [B*D] (unused), risk [B], time [B], event [B]
    const float* risk  = (const float*)d_in[1];
    const float* tim   = (const float*)d_in[2];
    const int*   event = (const int*)d_in[3];
    float*       out   = (float*)d_out;
    double*      ws    = (double*)d_ws;

    // d_ws is re-poisoned to 0xAA before every call — zero our accumulators.
    hipMemsetAsync(ws, 0, 2 * sizeof(double), stream);

    dim3 grid(BDIM / 256, BDIM / 256);  // 32 x 32 = 1024 blocks
    sgr_pair_kernel<<<grid, 256, 0, stream>>>(risk, tim, event, ws);
    sgr_finalize_kernel<<<1, 1, 0, stream>>>(ws, out);
}

// Round 2
// 84.204 us; speedup vs baseline: 1.0899x; 1.0899x over previous
//
#include <hip/hip_runtime.h>

// B=8192 all-pairs hinge ranking loss:
//   out = sum_{i,j} [ti<tj][ev_i] * relu(1 - (rj - ri)) / sum_{i,j} [ti<tj][ev_i]
// z (d_in[0]) unused.
//
// Structure: 2D grid (8 x 32). Each block: 256 threads x 4 i-rows, j-tile of
// 256 staged in LDS as float4 (wave-uniform broadcast reads, conflict-free).
// event folded into time via ti = ev ? ti : +inf (mask auto-false).
// Block partials -> double/uint device atomics -> last-block ticket finalizes.

#define MARGIN_F 1.0f
#define B_N   8192
#define TPB   256
#define IPT   4
#define JT    256
#define GRID_X (B_N / (TPB * IPT))   // 8
#define GRID_Y (B_N / JT)            // 32
#define NBLOCKS (GRID_X * GRID_Y)    // 256

struct Ws {
    double total;
    unsigned int cnt;
    unsigned int ticket;
};

__global__ __launch_bounds__(TPB) void sgr_kernel(
    const float* __restrict__ risk,
    const float* __restrict__ tim,
    const int*   __restrict__ event,
    Ws*          __restrict__ ws,
    float*       __restrict__ out)
{
    __shared__ float4 s_t4[JT / 4];
    __shared__ float4 s_r4[JT / 4];

    const int t     = threadIdx.x;
    const int jbase = blockIdx.y * JT;

    // Stage j-tile (coalesced float loads, TPB == JT).
    ((float*)s_t4)[t] = tim[jbase + t];
    ((float*)s_r4)[t] = risk[jbase + t];
    __syncthreads();

    const int ibase = blockIdx.x * (TPB * IPT);
    float ti[IPT], rip1[IPT], sum[IPT];
    unsigned int cnt[IPT];
    #pragma unroll
    for (int k = 0; k < IPT; ++k) {
        const int i  = ibase + k * TPB + t;       // coalesced
        const bool ev = (event[i] == 1);
        ti[k]   = ev ? tim[i] : __builtin_inff(); // +inf => ti<tj never => 0 contribution
        rip1[k] = risk[i] + MARGIN_F;
        sum[k]  = 0.0f;
        cnt[k]  = 0u;
    }

    #pragma unroll 4
    for (int c = 0; c < JT / 4; ++c) {
        const float4 t4 = s_t4[c];   // ds_read_b128, wave-uniform broadcast
        const float4 r4 = s_r4[c];
        const float tj[4] = {t4.x, t4.y, t4.z, t4.w};
        const float rj[4] = {r4.x, r4.y, r4.z, r4.w};
        #pragma unroll
        for (int u = 0; u < 4; ++u) {
            #pragma unroll
            for (int k = 0; k < IPT; ++k) {
                const bool  m = ti[k] < tj[u];
                const float h = fmaxf(rip1[k] - rj[u], 0.0f);
                sum[k] += m ? h : 0.0f;
                cnt[k] += m ? 1u : 0u;
            }
        }
    }

    float        s  = (sum[0] + sum[1]) + (sum[2] + sum[3]);
    unsigned int cu = (cnt[0] + cnt[1]) + (cnt[2] + cnt[3]);

    #pragma unroll
    for (int off = 32; off > 0; off >>= 1) {
        s  += __shfl_down(s, off, 64);
        cu += __shfl_down(cu, off, 64);
    }

    __shared__ float        w_s[TPB / 64];
    __shared__ unsigned int w_c[TPB / 64];
    const int wave = t >> 6, lane = t & 63;
    if (lane == 0) { w_s[wave] = s; w_c[wave] = cu; }
    __syncthreads();

    if (t == 0) {
        const float        bs = (w_s[0] + w_s[1]) + (w_s[2] + w_s[3]);
        const unsigned int bc = (w_c[0] + w_c[1]) + (w_c[2] + w_c[3]);
        atomicAdd(&ws->total, (double)bs);
        atomicAdd(&ws->cnt, bc);
        __threadfence();                                  // publish before ticket
        const unsigned int old = atomicAdd(&ws->ticket, 1u);
        if (old == NBLOCKS - 1) {
            // All 256 block-atomics complete & visible (each fenced before its
            // ticket increment). Re-read through atomics for coherence.
            const double       tot = atomicAdd(&ws->total, 0.0);
            const unsigned int cc  = atomicAdd(&ws->cnt, 0u);
            out[0] = cc ? (float)(tot / (double)cc) : 0.0f;
        }
    }
}

extern "C" void kernel_launch(void* const* d_in, const int* in_sizes, int n_in,
                              void* d_out, int out_size, void* d_ws, size_t ws_size,
                              hipStream_t stream)
{
    // setup_inputs order: z [B*D] (unused), risk [B], time [B], event [B]
    const float* risk  = (const float*)d_in[1];
    const float* tim   = (const float*)d_in[2];
    const int*   event = (const int*)d_in[3];
    float*       out   = (float*)d_out;
    Ws*          ws    = (Ws*)d_ws;

    hipMemsetAsync(ws, 0, sizeof(Ws), stream);   // zero accumulators + ticket

    dim3 grid(GRID_X, GRID_Y);
    sgr_kernel<<<grid, TPB, 0, stream>>>(risk, tim, event, ws, out);
}